// Round 6
// baseline (114.853 us; speedup 1.0000x reference)
//
#include <hip/hip_runtime.h>

#define NQ   12
#define DIM  4096
#define NL   4
#define BLK  256

typedef unsigned short u16;
typedef unsigned int   u32;
typedef float f2 __attribute__((ext_vector_type(2)));
typedef float f4v __attribute__((ext_vector_type(4)));

// ---------- compile-time GF(2) linear algebra for the CNOT-chain permutation ----------
struct L12 { u16 b[NQ]; };

static constexpr u32 lap(const L12& A, u32 x){ u32 r=0; for(int p=0;p<NQ;++p) if((x>>p)&1u) r^=A.b[p]; return r; }
static constexpr L12 lcomp(const L12& A, const L12& B){ L12 r{}; for(int p=0;p<NQ;++p) r.b[p]=(u16)lap(A,(u32)B.b[p]); return r; }
static constexpr L12 lident(){ L12 r{}; for(int p=0;p<NQ;++p) r.b[p]=(u16)(1u<<p); return r; }

static constexpr u32 applyT(u32 i){
  i ^= ((i>>0)&1u) << 11;                            // CNOT(11,0): bit11 ^= bit0
  for(int q=10;q>=0;--q){ int pc=11-q, pt=10-q; i ^= ((i>>pc)&1u) << pt; }
  return i;
}
static constexpr L12 lT(){ L12 t{}; for(int p=0;p<NQ;++p) t.b[p]=(u16)applyT(1u<<p); return t; }

static constexpr L12 linv(const L12& A){              // GF(2) Gauss-Jordan
  u16 v[NQ]; u16 u[NQ];
  for(int p=0;p<NQ;++p){ v[p]=A.b[p]; u[p]=(u16)(1u<<p); }
  for(int t=0;t<NQ;++t){
    int p=t; while(!((v[p]>>t)&1u)) ++p;
    u16 tv=v[p]; v[p]=v[t]; v[t]=tv; u16 tu=u[p]; u[p]=u[t]; u[t]=tu;
    for(int k=0;k<NQ;++k) if(k!=t && ((v[k]>>t)&1u)){ v[k]^=v[t]; u[k]^=u[t]; }
  }
  L12 r{}; for(int p=0;p<NQ;++p) r.b[p]=u[p]; return r;
}
static constexpr L12 ltr(const L12& A){
  L12 r{}; for(int p=0;p<NQ;++p) for(int q=0;q<NQ;++q) if((A.b[p]>>q)&1u) r.b[q]=(u16)(r.b[q]|(1u<<p));
  return r;
}
static constexpr int cpop(u32 v){ int n=0; while(v){ n+=(int)(v&1u); v>>=1; } return n; }

struct Tables {
  u16 cm[12][16];   // [step][combo] xor-offsets spanning the 4 gate masks
  u16 wg[12][4];    // [step][gate] parity mask: a0/a1 role selector
  u16 sp[12][4];    // [step] sorted pivot bit positions
  u16 wexp[NQ];     // final <Z> parity masks: rows of (T^4)^{-T}
};

static constexpr Tables make_tables(){
  Tables tb{};
  const L12 T   = lT();
  const L12 Tit = ltr(linv(T));   // T^{-T}
  L12 A = lident();               // A_l = T^l   (stored_index = A_l(true_index))
  L12 W = lident();               // W_l = A_l^{-T}
  for(int l=0;l<NL;++l){
    for(int g=0;g<3;++g){
      const int st = l*3+g;
      u16 mm[4]={0,0,0,0};
      for(int i=0;i<4;++i){ mm[i]=A.b[4*g+i]; tb.wg[st][i]=W.b[4*g+i]; }
      u32 ech[4]={0,0,0,0}; int piv[4]={0,0,0,0};
      for(int i=0;i<4;++i){
        u32 v=mm[i];
        for(int k=0;k<i;++k) if((v>>piv[k])&1u) v^=ech[k];
        int t2=11; while(!((v>>t2)&1u)) --t2;
        piv[i]=t2; ech[i]=v;
      }
      for(int a2=0;a2<4;++a2) for(int b2=a2+1;b2<4;++b2)
        if(piv[b2]<piv[a2]){ int tt=piv[a2]; piv[a2]=piv[b2]; piv[b2]=tt; }
      for(int i=0;i<4;++i) tb.sp[st][i]=(u16)piv[i];
      for(int c=0;c<16;++c){ u32 m=0; for(int i=0;i<4;++i) if((c>>i)&1) m^=mm[i]; tb.cm[st][c]=(u16)m; }
    }
    A = lcomp(A, T);
    W = lcomp(W, Tit);
  }
  for(int p=0;p<NQ;++p) tb.wexp[p]=W.b[p];
  return tb;
}

// ---------- LDS swizzle: slot = j ^ fold(j>>4), fold linear over GF(2) ----------
static constexpr u16 UIMG[12] = {1,2,4,8, 3,5,6,7, 9,10,11,13};

static constexpr u32 swz(u32 j){
  u32 f=0;
  for(int k=4;k<12;++k) if((j>>k)&1u) f ^= (u32)UIMG[k];
  return j ^ (f & 15u);
}

// rank of v[0..n) under bit-mask (≤4 bits)
static constexpr int rankbits(const u16* v, int n, u16 mask){
  u16 bas[4]={0,0,0,0}; int r=0;
  for(int i=0;i<n;++i){
    u16 x=(u16)(v[i]&mask);
    for(int it=0; it<5 && x; ++it){
      int hb=3; while(hb>0 && !((x>>hb)&1u)) --hb;
      if(bas[hb]) x=(u16)(x^bas[hb]); else { bas[hb]=x; ++r; x=0; }
    }
  }
  return r;
}

struct Derived {
  u32 lane_c[12][8];  // tid bit k -> (swz(1<<pos)<<4) | (role-parity nibble <<28)
  u32 smb[12][4];     // swz(cm[1<<i])<<4  (rep parity correction, swizzled)
  u32 scmb[12][16];   // swz(cm[c])<<4     (coset member byte offsets)
  u32 g0lane[8];      // step 0: unswizzled element-index contribution of tid bit k
  u32 u11lane[8];     // step 11: unswizzled index contribution of tid bit k
  u32 u11smb[4];      // step 11: unswizzled cm[1<<i]
  u16 pm[12];         // wexp[11-q]: per-thread parity mask on unswizzled rep
  u16 mu[12];         // Walsh index per output q
};

static constexpr Derived make_derived(){
  const Tables tb = make_tables();
  Derived d{};
  for(int st=0; st<12; ++st){
    bool isp[12]={false,false,false,false,false,false,false,false,false,false,false,false};
    for(int i=0;i<4;++i) isp[tb.sp[st][i]]=true;
    int np[8]; int nn=0;
    for(int p=0;p<12;++p) if(!isp[p]) np[nn++]=p;
    u16 img8[8];
    for(int j=0;j<8;++j) img8[j]=(u16)(swz(1u<<np[j])&15u);
    // ordering: lane bits 0-2 -> images rank-3 mod 8 (8-lane b128 phases),
    // lane bits 0-3 -> images rank-4 mod 16 (16-lane b64 phases)
    int ord[8]={0,1,2,3,4,5,6,7}; bool okf=false;
    for(int a=0;a<8&&!okf;++a)for(int b=a+1;b<8&&!okf;++b)
    for(int c2=b+1;c2<8&&!okf;++c2)for(int dd=c2+1;dd<8&&!okf;++dd){
      u16 four[4]={img8[a],img8[b],img8[c2],img8[dd]};
      if(rankbits(four,4,15)!=4) continue;
      const int ids[4]={a,b,c2,dd};
      for(int ex=0; ex<4 && !okf; ++ex){
        u16 tri[3]; int tj=0;
        for(int j=0;j<4;++j) if(j!=ex) tri[tj++]=four[j];
        if(rankbits(tri,3,7)!=3) continue;
        int pp=0;
        for(int j=0;j<4;++j) if(j!=ex) ord[pp++]=ids[j];
        ord[3]=ids[ex];
        int rp=4;
        for(int j=0;j<8;++j){
          bool used=false; for(int k2=0;k2<4;++k2) if(ids[k2]==j) used=true;
          if(!used) ord[rp++]=j;
        }
        okf=true;
      }
    }
    for(int k=0;k<8;++k){
      const int pos = np[ord[k]];
      const u32 addr = swz(1u<<pos)<<4;
      u32 nib=0;
      for(int i=0;i<4;++i) nib |= (u32)((tb.wg[st][i]>>pos)&1u)<<i;
      d.lane_c[st][k] = addr | (nib<<28);
      if(st==0)  d.g0lane[k]  = 1u<<pos;
      if(st==11) d.u11lane[k] = 1u<<pos;
    }
    for(int i=0;i<4;++i)  d.smb[st][i]  = swz((u32)tb.cm[st][1<<i])<<4;
    for(int c=0;c<16;++c) d.scmb[st][c] = swz((u32)tb.cm[st][c])<<4;
    if(st==11) for(int i=0;i<4;++i) d.u11smb[i] = (u32)tb.cm[11][1<<i];
  }
  for(int q=0;q<12;++q){
    d.pm[q] = tb.wexp[11-q];
    u32 m=0;
    for(int i=0;i<4;++i) m |= (u32)(cpop((u32)tb.cm[11][1u<<i] & (u32)tb.wexp[11-q])&1)<<i;
    d.mu[q]=(u16)m;
  }
  return d;
}

__device__ constexpr Derived DV = make_derived();

// ---------- packed f32 helpers (forced v_pk_fma_f32) ----------
__device__ __forceinline__ f2 pkfma(f2 a, f2 b, f2 c){
  f2 d;
  asm("v_pk_fma_f32 %0, %1, %2, %3" : "=v"(d) : "v"(a), "v"(b), "v"(c));
  return d;
}

// ---------- 4 commuting gates, 2 batch rows packed per component ----------
// R/I hold {row0,row1}. 3-shear RY + 3-shear RZ, all v_pk_fma_f32.
// gw[g] = {-tan(ty/4), sin(ty/2), -tan(tz/2), sin(tz)}  (global phase dropped)
template<int ST, bool WITHW>
__device__ __forceinline__ void gates(f2 (&R)[16], f2 (&I)[16], const float4* __restrict__ gw){
#pragma unroll
  for(int i=0;i<4;++i){
    const float4 g = gw[ST*4+i];
    const f2 mt  = {g.x, g.x};
    const f2 sy  = {g.y, g.y};
    const f2 mgz = {g.z, g.z};
    const f2 sw  = {g.w, g.w};
#pragma unroll
    for(int c=0;c<16;++c){
      if((c>>i)&1) continue;
      const int c1 = c|(1<<i);
      f2 uR = pkfma(mt, R[c1], R[c]);      // u  = a0 - t*a1
      f2 uI = pkfma(mt, I[c1], I[c]);
      f2 vR = pkfma(sy, uR, R[c1]);        // a1'= a1 + s*u
      f2 vI = pkfma(sy, uI, I[c1]);
      R[c] = pkfma(mt, vR, uR);            // a0'= u - t*a1'
      I[c] = pkfma(mt, vI, uI);
      if(WITHW){                           // rotate (vR,vI) by +tz (3-shear)
        const f2 tr = pkfma(mgz, vI, vR);
        vI = pkfma(sw, tr, vI);
        vR = pkfma(mgz, vI, tr);
      }
      R[c1]=vR; I[c1]=vI;
    }
  }
}

template<int ST, bool WITHW>
__device__ __forceinline__ void mid_step(const u32* msk, char* lds, const float4* __restrict__ gw){
  u32 acc=0;
#pragma unroll
  for(int k=0;k<8;++k) acc ^= DV.lane_c[ST][k]&msk[k];
  const u32 nib = acc>>28;
  u32 base = acc & 0x0FFFFFFFu;
#pragma unroll
  for(int i=0;i<4;++i) base ^= DV.smb[ST][i] & (0u-((nib>>i)&1u));
  u32 ad[16]; f2 R[16], I[16];
#pragma unroll
  for(int c=0;c<16;++c){
    ad[c] = base ^ DV.scmb[ST][c];
    const f4v v = *(const f4v*)(lds+ad[c]);
    R[c]=v.lo; I[c]=v.hi;
  }
  gates<ST,WITHW>(R,I,gw);
#pragma unroll
  for(int c=0;c<16;++c){ f4v v; v.lo=R[c]; v.hi=I[c]; *(f4v*)(lds+ad[c]) = v; }
  __syncthreads();
}

__global__ void prep_kernel(const float* __restrict__ w, float4* __restrict__ gw){
  const int t = threadIdx.x;
  if(t < NL*NQ){
    const int l=t/NQ, p=t%NQ, q=(NQ-1)-p;
    const float ty=w[(l*NQ+q)*2+0], tz=w[(l*NQ+q)*2+1];
    gw[t]=make_float4(-tanf(0.25f*ty), sinf(0.5f*ty), -tanf(0.5f*tz), sinf(tz));
  }
}

__global__ __launch_bounds__(BLK, 2) void qsim_kernel(const float* __restrict__ x,
                                                      const float4* __restrict__ gw,
                                                      float* __restrict__ out)
{
  __shared__ f4v st4[DIM];             // 65536 B: {re0,re1,im0,im1} per basis state
  char* lds = (char*)st4;
  const int tid = threadIdx.x;
  const int bb  = blockIdx.x;

  u32 msk[8];
#pragma unroll
  for(int k=0;k<8;++k) msk[k]=0u-((u32)(tid>>k)&1u);

  // ---- step 0: masks are bits 0..3 -> coset = 16 consecutive floats in global ----
  u32 rep0=0, acc0=0;
#pragma unroll
  for(int k=0;k<8;++k){ rep0 ^= DV.g0lane[k]&msk[k]; acc0 ^= DV.lane_c[0][k]&msk[k]; }
  const u32 base0 = acc0 & 0x0FFFFFFFu;   // nib == 0 at step 0

  f2 R[16], I[16];
  const float* xr0 = x + (size_t)(2*bb)*DIM + rep0;
  const float* xr1 = xr0 + DIM;
#pragma unroll
  for(int s=0;s<4;++s){
    const float4 v0 = *reinterpret_cast<const float4*>(xr0 + 4*s);
    const float4 v1 = *reinterpret_cast<const float4*>(xr1 + 4*s);
    R[4*s+0]=(f2){v0.x,v1.x}; R[4*s+1]=(f2){v0.y,v1.y};
    R[4*s+2]=(f2){v0.z,v1.z}; R[4*s+3]=(f2){v0.w,v1.w};
    I[4*s+0]=(f2){0.f,0.f};   I[4*s+1]=(f2){0.f,0.f};
    I[4*s+2]=(f2){0.f,0.f};   I[4*s+3]=(f2){0.f,0.f};
  }
  gates<0,true>(R,I,gw);
#pragma unroll
  for(int c=0;c<16;++c){ f4v v; v.lo=R[c]; v.hi=I[c];
    *(f4v*)(lds + (base0 ^ DV.scmb[0][c])) = v; }
  __syncthreads();

  // ---- steps 1..10: LDS round trips ----
  mid_step<1,true >(msk,lds,gw);
  mid_step<2,true >(msk,lds,gw);
  mid_step<3,true >(msk,lds,gw);
  mid_step<4,true >(msk,lds,gw);
  mid_step<5,true >(msk,lds,gw);
  mid_step<6,true >(msk,lds,gw);
  mid_step<7,true >(msk,lds,gw);
  mid_step<8,true >(msk,lds,gw);
  mid_step<9,false>(msk,lds,gw);     // last layer: RZ phase dropped (|amp|^2 readout)
  mid_step<10,false>(msk,lds,gw);

  // ---- step 11 + fused Walsh readout (no write-back) ----
  {
    u32 acc=0, urep=0;
#pragma unroll
    for(int k=0;k<8;++k){ acc ^= DV.lane_c[11][k]&msk[k]; urep ^= DV.u11lane[k]&msk[k]; }
    const u32 nib = acc>>28;
    u32 base = acc & 0x0FFFFFFFu;
#pragma unroll
    for(int i=0;i<4;++i){ const u32 mi=0u-((nib>>i)&1u); base ^= DV.smb[11][i]&mi; urep ^= DV.u11smb[i]&mi; }
#pragma unroll
    for(int c=0;c<16;++c){
      const f4v v = *(const f4v*)(lds + (base ^ DV.scmb[11][c]));
      R[c]=v.lo; I[c]=v.hi;
    }
    gates<11,false>(R,I,gw);

    f2 pr[16];
#pragma unroll
    for(int c=0;c<16;++c) pr[c]=pkfma(R[c],R[c], pkfma(I[c],I[c],(f2){0.f,0.f}));
    // Walsh-Hadamard over the 4 combo bits: W[m] = sum_c (-1)^{popc(c&m)} pr[c]
    const f2 mone = {-1.f,-1.f};
#pragma unroll
    for(int b=1;b<16;b<<=1){
#pragma unroll
      for(int c=0;c<16;++c){
        if(c&b) continue;
        const f2 u=pr[c], v=pr[c|b];
        pr[c]=u+v;
        pr[c|b]=pkfma(v,mone,u);
      }
    }
    f2 accq[12];
#pragma unroll
    for(int q=0;q<12;++q){
      const u32 sb = ((u32)__popc(urep & (u32)DV.pm[q]) & 1u)<<31;
      const f2 a = pr[DV.mu[q]];
      accq[q]=(f2){__uint_as_float(__float_as_uint(a.x)^sb),
                   __uint_as_float(__float_as_uint(a.y)^sb)};
    }
    f2 nrm2 = pr[0];
#pragma unroll
    for(int o=32;o;o>>=1){
      nrm2.x += __shfl_xor(nrm2.x,o);
      nrm2.y += __shfl_xor(nrm2.y,o);
#pragma unroll
      for(int q=0;q<12;++q){
        accq[q].x += __shfl_xor(accq[q].x,o);
        accq[q].y += __shfl_xor(accq[q].y,o);
      }
    }
    __syncthreads();                      // all waves done reading step 11
    f2* wredp = (f2*)lds;                 // alias reduction buffer into state LDS
    const int wid=tid>>6;
    if((tid&63)==0){
#pragma unroll
      for(int q=0;q<12;++q) wredp[wid*13+q]=accq[q];
      wredp[wid*13+12]=nrm2;
    }
    __syncthreads();
    if(tid<NQ){
      const f2 s0=wredp[0*13+tid]+wredp[1*13+tid]+wredp[2*13+tid]+wredp[3*13+tid];
      const f2 sn=wredp[0*13+12]+wredp[1*13+12]+wredp[2*13+12]+wredp[3*13+12];
      out[(size_t)(2*bb+0)*NQ+tid]=s0.x/sn.x;
      out[(size_t)(2*bb+1)*NQ+tid]=s0.y/sn.y;
    }
  }
}

extern "C" void kernel_launch(void* const* d_in, const int* in_sizes, int n_in,
                              void* d_out, int out_size, void* d_ws, size_t ws_size,
                              hipStream_t stream) {
  const float* x = (const float*)d_in[0];
  const float* w = (const float*)d_in[1];
  float* out = (float*)d_out;
  float4* gw = (float4*)d_ws;
  const int B = in_sizes[0] / DIM;
  prep_kernel<<<1, 64, 0, stream>>>(w, gw);
  qsim_kernel<<<B/2, BLK, 0, stream>>>(x, gw, out);
}